// Round 8
// baseline (114.403 us; speedup 1.0000x reference)
//
#include <hip/hip_runtime.h>

#define B_SZ   4096
#define H_SZ   200
#define D_SZ   128
#define N_SZ   256
#define ROWS   (B_SZ * H_SZ)      // 819200
#define BM     64
#define TPB    8                  // tiles per block
#define RPB    (BM * TPB)         // 512 rows per block
#define NBLK   (ROWS / RPB)       // 1600

typedef _Float16 f16;
typedef __attribute__((ext_vector_type(2))) _Float16 f16x2;
typedef __attribute__((ext_vector_type(8))) _Float16 f16x8;
typedef __attribute__((ext_vector_type(4))) float f32x4;

union H8 { f16x8 v; f16x2 p[4]; uint4 u; };

__device__ __forceinline__ f16x2 pkrtz(float a, float b) {
    return __builtin_bit_cast(f16x2, __builtin_amdgcn_cvt_pkrtz(a, b));
}

// Kernel 0a: embed_history f32 -> f16 (RTZ pack), 8 elems/thread
__global__ __launch_bounds__(256) void cvt_eh(const float* __restrict__ src,
                                              uint4* __restrict__ dst, int n8) {
    int i = blockIdx.x * 256 + threadIdx.x;
    if (i >= n8) return;
    const f32x4* p = (const f32x4*)src + (size_t)i * 2;
    f32x4 a = p[0], b = p[1];
    uint4 o;
    o.x = __builtin_bit_cast(unsigned, pkrtz(a[0], a[1]));
    o.y = __builtin_bit_cast(unsigned, pkrtz(a[2], a[3]));
    o.z = __builtin_bit_cast(unsigned, pkrtz(b[0], b[1]));
    o.w = __builtin_bit_cast(unsigned, pkrtz(b[2], b[3]));
    dst[i] = o;
}

// Kernel 0b: W1 [128][256] f32 -> W1T/16 [256][128] f16
__global__ __launch_bounds__(256) void cvt_w1(const float* __restrict__ src,
                                              f16* __restrict__ dst) {
    int i = blockIdx.x * 256 + threadIdx.x;   // i = n*128 + d
    int n = i >> 7, d = i & 127;
    dst[i] = (f16)(src[d * N_SZ + n] * 0.0625f);
}

// Main: 256 thr = 4 waves; wave w owns N-cols [64w, 64w+64)  (halves A-tile
// LDS read redundancy vs 8-wave n=32). Construct thread (row=tid>>2, seg=tid&3)
// covers d in [32seg, 32seg+32).
__global__ __launch_bounds__(256, 3) void nais_main(
    const int* __restrict__ history, const int* __restrict__ target,
    const uint4* __restrict__ ehh, const float* __restrict__ et,
    const f16* __restrict__ w1t, const float* __restrict__ b1,
    const float* __restrict__ w2,
    float* __restrict__ a_out, float* __restrict__ dotd_out)
{
    __shared__ uint4 AbufV[2][BM * 256 / 16];  // 32 KB swizzled [64][128] f16 x2
    __shared__ float apart[2][4][BM];          // 2 KB
    __shared__ f16   tgt_h[4][D_SZ];           // 1 KB (t * 16, f16)
    __shared__ int   tgt_i[4];

    const int tid  = threadIdx.x;
    const int wid  = tid >> 6;
    const int lane = tid & 63;
    const int lo   = lane & 15;
    const int hi   = lane >> 4;
    const int row  = tid >> 2;
    const int seg  = tid & 3;
    const int blk  = blockIdx.x;
    const int b_base = (blk * RPB) / H_SZ;

    if (tid < 4) {
        int bb = b_base + tid;
        tgt_i[tid] = target[bb < B_SZ ? bb : (B_SZ - 1)];
    }
    __syncthreads();
    {   // preload 4 target rows as f16 * 16 (256 threads cover 4*64 f16x2)
        const int r4 = tid >> 6, j = (tid & 63) * 2;
        const float* src = et + (size_t)tgt_i[r4] * D_SZ + j;
        ((f16x2*)tgt_h)[tid] = pkrtz(src[0] * 16.f, src[1] * 16.f);
    }

    // W1T/16 fragments: wave wid owns cols [64*wid, 64*wid+64)
    f16x8 wfrag[4][4];
    #pragma unroll
    for (int ni = 0; ni < 4; ++ni) {
        int n = 64 * wid + 16 * ni + lo;
        #pragma unroll
        for (int ki = 0; ki < 4; ++ki)
            wfrag[ki][ni] = *(const f16x8*)(w1t + (size_t)n * D_SZ + 32 * ki + 8 * hi);
    }
    // b1 / w2 per-lane: n = 64wid + 16ni + 4hi + r
    const int n0 = 64 * wid + 4 * hi;
    f32x4 b1v[4], w2v[4];
    #pragma unroll
    for (int ni = 0; ni < 4; ++ni) {
        b1v[ni] = *(const f32x4*)(b1 + n0 + 16 * ni);
        w2v[ni] = *(const f32x4*)(w2 + n0 + 16 * ni);
    }

    // gather pipeline prologue: thread loads 64B of its row (d-block 32*seg..+32)
    const int grow0 = blk * RPB + row;
    const int* hrow = history + grow0;
    int ih_cur = hrow[0];
    int ih_nxt = hrow[BM];
    uint4 hq0, hq1, hq2, hq3;
    {
        const uint4* p = ehh + (size_t)ih_cur * 16 + 4 * seg;
        hq0 = p[0]; hq1 = p[1]; hq2 = p[2]; hq3 = p[3];
    }
    // incremental b_loc
    int b_loc = grow0 / H_SZ - b_base;
    int rem   = grow0 - (b_loc + b_base) * H_SZ;
    __syncthreads();   // tgt_h ready

    for (int t = 0; t < TPB; ++t) {
        char* Ab = (char*)AbufV[t & 1];
        const int gr = grow0 + t * BM;

        // ---- construct tile t: 32 elems/thread, f16 packed ----
        {
            const f16x8* tp = (const f16x8*)&tgt_h[b_loc][32 * seg];
            const unsigned sw = (unsigned)((row & 7) << 4);
            char* rb = Ab + row * 256;
            float s = 0.f;
            #define CONS(J, HQ) { H8 h, tt, x; h.u = HQ; tt.v = tp[J]; x.v = h.v * tt.v; \
                s = __builtin_amdgcn_fdot2(h.p[0], tt.p[0], s, false); \
                s = __builtin_amdgcn_fdot2(h.p[1], tt.p[1], s, false); \
                s = __builtin_amdgcn_fdot2(h.p[2], tt.p[2], s, false); \
                s = __builtin_amdgcn_fdot2(h.p[3], tt.p[3], s, false); \
                *(uint4*)(rb + (((unsigned)(64 * seg + 16 * J)) ^ sw)) = x.u; }
            CONS(0, hq0) CONS(1, hq1) CONS(2, hq2) CONS(3, hq3)
            #undef CONS
            s += __shfl_xor(s, 1);
            s += __shfl_xor(s, 2);
            if (seg == 0) dotd_out[gr] = s * 0.0625f;
        }
        __syncthreads();   // [single barrier per tile]

        // ---- prefetch next tile's gathers (hide under MFMA) ----
        if (t + 1 < TPB) {
            ih_cur = ih_nxt;
            if (t + 2 < TPB) ih_nxt = hrow[(t + 2) * BM];
            const uint4* p = ehh + (size_t)ih_cur * 16 + 4 * seg;
            hq0 = p[0]; hq1 = p[1]; hq2 = p[2]; hq3 = p[3];
        }

        // ---- lagged reduction of tile t-1's apart (4 planes) ----
        if (t > 0 && tid < BM) {
            const float* ap = &apart[(t - 1) & 1][0][tid];
            float a = ap[0] + ap[BM] + ap[2 * BM] + ap[3 * BM];
            a_out[blk * RPB + (t - 1) * BM + tid] = a;
        }

        // ---- swapped MFMA (4 indep acc chains) + epilogue ----
        #pragma unroll
        for (int mi = 0; mi < 4; ++mi) {
            const int rr = 16 * mi + lo;
            const unsigned swr = (unsigned)((rr & 7) << 4);
            f16x8 af[4];
            #pragma unroll
            for (int ki = 0; ki < 4; ++ki) {
                unsigned off = ((unsigned)(64 * ki + 16 * hi)) ^ swr;
                af[ki] = *(const f16x8*)(Ab + rr * 256 + off);
            }
            f32x4 acc0 = b1v[0], acc1 = b1v[1], acc2 = b1v[2], acc3 = b1v[3];
            __builtin_amdgcn_s_setprio(1);
            #pragma unroll
            for (int ki = 0; ki < 4; ++ki) {
                acc0 = __builtin_amdgcn_mfma_f32_16x16x32_f16(wfrag[ki][0], af[ki], acc0, 0, 0, 0);
                acc1 = __builtin_amdgcn_mfma_f32_16x16x32_f16(wfrag[ki][1], af[ki], acc1, 0, 0, 0);
                acc2 = __builtin_amdgcn_mfma_f32_16x16x32_f16(wfrag[ki][2], af[ki], acc2, 0, 0, 0);
                acc3 = __builtin_amdgcn_mfma_f32_16x16x32_f16(wfrag[ki][3], af[ki], acc3, 0, 0, 0);
            }
            __builtin_amdgcn_s_setprio(0);
            // lane lo = x-row (16mi+lo); regs r of acc_ni = N-col 64wid+16ni+4hi+r
            float v = 0.f;
            #define EPI(ACC, NI) \
                v += fmaxf(ACC[0], 0.f) * w2v[NI][0] + fmaxf(ACC[1], 0.f) * w2v[NI][1] \
                   + fmaxf(ACC[2], 0.f) * w2v[NI][2] + fmaxf(ACC[3], 0.f) * w2v[NI][3];
            EPI(acc0, 0) EPI(acc1, 1) EPI(acc2, 2) EPI(acc3, 3)
            #undef EPI
            v += __shfl_xor(v, 16);
            v += __shfl_xor(v, 32);
            if (lane < 16) apart[t & 1][wid][16 * mi + lane] = v;
        }

        // advance incremental b_loc (row += 64)
        rem += BM;
        if (rem >= H_SZ) { rem -= H_SZ; ++b_loc; }
    }
    __syncthreads();
    if (tid < BM) {   // final tile's reduction
        const float* ap = &apart[(TPB - 1) & 1][0][tid];
        float a = ap[0] + ap[BM] + ap[2 * BM] + ap[3 * BM];
        a_out[blk * RPB + (TPB - 1) * BM + tid] = a;
    }
}

// Finish: per-b masked exp, beta=0.5 power norm, weighted dot, sigmoid
__global__ __launch_bounds__(64) void nais_finish(
    const int* __restrict__ history, const int* __restrict__ target,
    const float* __restrict__ a_in, const float* __restrict__ dotd_in,
    float* __restrict__ out)
{
    const int b    = blockIdx.x;
    const int lane = threadIdx.x;
    const int tgt  = target[b];
    float s1 = 0.f, s2 = 0.f;
    for (int h = lane; h < H_SZ; h += 64) {
        int rg = b * H_SZ + h;
        float e = (history[rg] != tgt) ? __expf(a_in[rg]) : 0.f;
        s1 += e;
        s2 += e * dotd_in[rg];
    }
    #pragma unroll
    for (int o = 1; o < 64; o <<= 1) {
        s1 += __shfl_xor(s1, o);
        s2 += __shfl_xor(s2, o);
    }
    if (lane == 0) {
        float pred = s2 / sqrtf(s1);
        out[b] = 1.f / (1.f + __expf(-pred));
    }
}

extern "C" void kernel_launch(void* const* d_in, const int* in_sizes, int n_in,
                              void* d_out, int out_size, void* d_ws, size_t ws_size,
                              hipStream_t stream) {
    const int*   history = (const int*)d_in[0];
    const int*   target  = (const int*)d_in[1];
    const float* eh      = (const float*)d_in[2];
    const float* et      = (const float*)d_in[3];
    const float* W1      = (const float*)d_in[4];
    const float* b1      = (const float*)d_in[5];
    const float* w2      = (const float*)d_in[6];
    float* out = (float*)d_out;

    char* ws = (char*)d_ws;
    uint4* ehh = (uint4*)ws;                                     // 25.6 MB (f16)
    f16*   w1t = (f16*)(ws + (size_t)100000 * D_SZ * 2);         // 64 KB
    float* a_ws = (float*)(ws + (size_t)100000 * D_SZ * 2 + N_SZ * D_SZ * 2);
    float* dotd_ws = a_ws + ROWS;

    const int n8 = 100000 * D_SZ / 8;
    cvt_eh<<<(n8 + 255) / 256, 256, 0, stream>>>(eh, ehh, n8);
    cvt_w1<<<(N_SZ * D_SZ) / 256, 256, 0, stream>>>(W1, w1t);
    nais_main<<<NBLK, 256, 0, stream>>>(history, target, ehh, et, w1t, b1, w2, a_ws, dotd_ws);
    nais_finish<<<B_SZ, 64, 0, stream>>>(history, target, a_ws, dotd_ws, out);
}